// Round 5
// baseline (769.243 us; speedup 1.0000x reference)
//
#include <hip/hip_runtime.h>
#include <cstdint>
#include <cstddef>

#define T_TOK 4096
#define HD 2048
#define ID 1408
#define NE 8
#define NA (T_TOK * 2)        // 8192 assignments (K=2)
#define MAXR 10240            // 8192 + 8*255 padding headroom, mult of 256
#define MAXT 40               // max 256-row tiles (<= 39 actually)
#define NTILE_G (MAXR / 256)  // 40
#define NGEMM_GU (NTILE_G * (ID / 128))  // 440 (divisible by 8 -> bijective XCD swizzle)
#define NKGU (HD / 64)        // 32 K-tiles (BK=64)
#define NKD  (ID / 64)        // 22 K-tiles

typedef __bf16 bf16x8 __attribute__((ext_vector_type(8)));
typedef float f32x4 __attribute__((ext_vector_type(4)));

#define MFMA16 __builtin_amdgcn_mfma_f32_16x16x32_bf16
#define LD8(base, off) (*(const bf16x8*)&(base)[(off)])

__device__ __forceinline__ unsigned short f2bf(float f) {
  union { float f; unsigned int u; } c; c.f = f;
  unsigned int u = c.u;
  u += 0x7fffu + ((u >> 16) & 1u);   // round-to-nearest-even
  return (unsigned short)(u >> 16);
}

// v_cvt_pk_bf16_f32: dst.lo16 = bf16(lo), dst.hi16 = bf16(hi), RNE (== f2bf)
__device__ __forceinline__ unsigned int cvtpk(float lo, float hi) {
  unsigned int r;
  asm volatile("v_cvt_pk_bf16_f32 %0, %1, %2" : "=v"(r) : "v"(lo), "v"(hi));
  return r;
}

__device__ __forceinline__ uint4 cvt8(const f32x4& v0, const f32x4& v1) {
  uint4 w;
  w.x = cvtpk(v0[0], v0[1]); w.y = cvtpk(v0[2], v0[3]);
  w.z = cvtpk(v1[0], v1[1]); w.w = cvtpk(v1[2], v1[3]);
  return w;
}

__device__ __forceinline__ void gl_lds16(const unsigned short* g, unsigned short* l) {
  __builtin_amdgcn_global_load_lds(
      (const __attribute__((address_space(1))) unsigned int*)g,
      (__attribute__((address_space(3))) unsigned int*)l, 16, 0, 0);
}

// XOR-swizzled [256]x[32] bf16 slab (64B rows, swizzle at 128B/2-row units):
// logical (row R, 16B chunk fq) lives at physical chunk p = q ^ ((R>>1)&7),
// q = (R&1)*4 + fq. Measured conflict-free (SQ_LDS_BANK_CONFLICT = 0).
__device__ __forceinline__ int swz_off(int R, int fq) {
  int q = ((R & 1) << 2) | fq;
  int p = q ^ ((R >> 1) & 7);
  return (R >> 1) * 64 + p * 8;
}
// buf layout: 2 K-slabs of [256 phys rows][32 elems]; ks selects slab.
__device__ __forceinline__ int lds_off(int ks, int P, int fq) {
  return ks * 8192 + swz_off(P, fq);
}

// ---------------- routing: single-block fused count+scan+fill ---------------
__global__ void moe_route(const int* __restrict__ idx, const float* __restrict__ wts,
                          int* __restrict__ work_e, int* __restrict__ work_r,
                          int* __restrict__ ntiles,
                          int* __restrict__ row_token, float* __restrict__ row_weight) {
  __shared__ int off_s[256 * 8];
  __shared__ int seg_s[8];
  __shared__ int cnt_s[8];
  const int tid = threadIdx.x;
  // init all row slots invalid
  for (int i = tid; i < MAXR; i += 256) row_token[i] = -1;
#pragma unroll
  for (int e = 0; e < 8; ++e) off_s[tid * 8 + e] = 0;
  const int a0 = tid * 32;           // 256 threads x 32 = 8192 assignments
  for (int j = 0; j < 32; ++j) off_s[tid * 8 + idx[a0 + j]]++;
  __syncthreads();
  if (tid < 8) {                     // exclusive scan over threads, per expert
    int run = 0;
    for (int t = 0; t < 256; ++t) {
      int v = off_s[t * 8 + tid]; off_s[t * 8 + tid] = run; run += v;
    }
    cnt_s[tid] = run;
  }
  __syncthreads();
  if (tid == 0) {
    int off = 0, nt = 0;
    for (int e = 0; e < NE; ++e) {
      seg_s[e] = off;
      int tiles = (cnt_s[e] + 255) >> 8;   // pad each expert to 256-row tiles
      for (int tb = 0; tb < tiles; ++tb) { work_e[nt] = e; work_r[nt] = off + tb * 256; ++nt; }
      off += tiles << 8;
    }
    *ntiles = nt;
  }
  __syncthreads();
  for (int j = 0; j < 32; ++j) {     // deterministic emit
    int a = a0 + j;
    int e = idx[a];
    int slot = seg_s[e] + off_s[tid * 8 + e]++;
    row_token[slot] = a >> 1;        // token id (K=2)
    row_weight[slot] = wts[a];
  }
}

// ---------------- gate+up GEMM: fp32 inputs, in-register cast ---------------
// Tile 256 rows x 128 I-cols of BOTH gate and up. 512 thr / 8 waves (2M x 4N).
// A read DIRECTLY from hidden fp32 via token indirection; B from gate/up fp32.
// Staging: global_load_dwordx4 x2 -> cvt_pk_bf16 x4 -> ds_write_b128 to the
// same swizzled layout gl_lds produced. Prefetch distance 1 K-tile; counted
// vmcnt(8) at P1 (A) and P3 (B); ds_write visibility via per-phase lgkmcnt(0).
__global__ __launch_bounds__(512, 2) void moe_gateup(
    const float* __restrict__ hidden,
    const float* __restrict__ Wg, const float* __restrict__ Wu,
    unsigned short* __restrict__ inter,
    const int* __restrict__ work_e, const int* __restrict__ work_r,
    const int* __restrict__ ntiles, const int* __restrict__ row_token) {
  const int bx = blockIdx.x;
  // bijective XCD swizzle (440 % 8 == 0)
  const int g = (bx & 7) * (NGEMM_GU / 8) + (bx >> 3);
  const int tile = g % NTILE_G;
  if (tile >= *ntiles) return;
  const int e = work_e[tile];
  const int row0 = work_r[tile];
  const int col0 = (g / NTILE_G) * 128;

  __shared__ unsigned short As[2][16384];   // 64 KB
  __shared__ unsigned short Bs[2][16384];   // 64 KB (phys rows 0-127 gate, 128-255 up)
  __shared__ int tok_s[256];

  const int tid = threadIdx.x;
  const int lane = tid & 63;
  const int wave = tid >> 6;          // 0..7
  const int wm = wave >> 2, wn = wave & 3;
  const int p_l = lane & 7;
  const int ub  = lane >> 3;
  const int q_l = p_l ^ ub;
  const int srow = (ub << 1) | (q_l >> 2);
  const int scol = (q_l & 3) << 3;    // bf16-elem offset within 64-elem row
  const int fm = lane & 15, fq = lane >> 4;

  if (tid < 256) { int tk = row_token[row0 + tid]; tok_s[tid] = tk < 0 ? 0 : tk; }
  __syncthreads();

  const size_t b_base = ((size_t)e * ID + col0) * HD;
  size_t rowAoff[2];
#pragma unroll
  for (int h = 0; h < 2; ++h) {
    int r = ((wave >> 2) << 7) + (h << 6) + ((wave & 3) << 4) + srow;
    rowAoff[h] = (size_t)tok_s[r] * HD;
  }
  const float* pB[2] = { Wg + b_base + (size_t)((wave << 4) + srow) * HD,
                         Wu + b_base + (size_t)((wave << 4) + srow) * HD };

  f32x4 rA[2][2][2], rB[2][2][2];    // [h][s][p] staging regs (64 VGPR)

  auto loadA = [&](int k0) {
#pragma unroll
    for (int h = 0; h < 2; ++h)
#pragma unroll
      for (int s = 0; s < 2; ++s)
#pragma unroll
        for (int p = 0; p < 2; ++p)
          rA[h][s][p] = *(const f32x4*)(hidden + rowAoff[h] + k0 + s * 32 + scol + p * 4);
  };
  auto loadB = [&](int k0) {
#pragma unroll
    for (int h = 0; h < 2; ++h)
#pragma unroll
      for (int s = 0; s < 2; ++s)
#pragma unroll
        for (int p = 0; p < 2; ++p)
          rB[h][s][p] = *(const f32x4*)(pB[h] + k0 + s * 32 + scol + p * 4);
  };
  auto writeA = [&](int b) {
#pragma unroll
    for (int h = 0; h < 2; ++h) {
      const int pp = (h << 7) + (wave << 4);
#pragma unroll
      for (int s = 0; s < 2; ++s)
        *(uint4*)&As[b][s * 8192 + pp * 32 + lane * 8] = cvt8(rA[h][s][0], rA[h][s][1]);
    }
  };
  auto writeB = [&](int b) {
#pragma unroll
    for (int h = 0; h < 2; ++h) {
      const int pp = (h << 7) + (wave << 4);
#pragma unroll
      for (int s = 0; s < 2; ++s)
        *(uint4*)&Bs[b][s * 8192 + pp * 32 + lane * 8] = cvt8(rB[h][s][0], rB[h][s][1]);
    }
  };

  f32x4 zero = {0.f, 0.f, 0.f, 0.f};
  f32x4 accg[8][2], accu[8][2];
#pragma unroll
  for (int mi = 0; mi < 8; ++mi)
#pragma unroll
    for (int j = 0; j < 2; ++j) { accg[mi][j] = zero; accu[mi][j] = zero; }

  // prologue: tile 0 loaded+written; tile 1 loads in flight (16)
  loadA(0); loadB(0);
  asm volatile("s_waitcnt vmcnt(0)" ::: "memory");
  writeA(0); writeB(0);
  loadA(64); loadB(64);
  asm volatile("s_waitcnt lgkmcnt(0)" ::: "memory");
  __builtin_amdgcn_s_barrier();

  bf16x8 a[4][2], bg[2][2], bu[2][2];
#pragma unroll 1
  for (int t = 0; t < NKGU; ++t) {
    const int k2 = (t + 2) << 6;
    const bool pf = (t + 1 < NKGU);
    const bool pf2 = (t + 2 < NKGU);
    const unsigned short* Ab = As[t & 1];
    const unsigned short* Bb = Bs[t & 1];
    const int bn = (t & 1) ^ 1;

    // ---- P1: read A-m0 + bg | wait A(t+1), write, issue A(t+2) | MFMA g-m0
#pragma unroll
    for (int i = 0; i < 4; ++i)
#pragma unroll
      for (int ks = 0; ks < 2; ++ks)
        a[i][ks] = LD8(Ab, lds_off(ks, wm * 64 + i * 16 + fm, fq));
#pragma unroll
    for (int j = 0; j < 2; ++j)
#pragma unroll
      for (int ks = 0; ks < 2; ++ks)
        bg[j][ks] = LD8(Bb, lds_off(ks, wn * 32 + j * 16 + fm, fq));
    if (pf) {
      asm volatile("s_waitcnt vmcnt(8)" ::: "memory");   // A(t+1) landed, B(t+1) in flight
      writeA(bn);
      if (pf2) loadA(k2);
    }
    __builtin_amdgcn_s_barrier();
    asm volatile("s_waitcnt lgkmcnt(0)" ::: "memory");
    __builtin_amdgcn_sched_barrier(0);
    __builtin_amdgcn_s_setprio(1);
#pragma unroll
    for (int mi = 0; mi < 4; ++mi)
#pragma unroll
      for (int j = 0; j < 2; ++j)
#pragma unroll
        for (int ks = 0; ks < 2; ++ks)
          accg[mi][j] = MFMA16(a[mi][ks], bg[j][ks], accg[mi][j], 0, 0, 0);
    __builtin_amdgcn_s_setprio(0);
    __builtin_amdgcn_s_barrier();

    // ---- P2: read bu | MFMA u-m0 ----
#pragma unroll
    for (int j = 0; j < 2; ++j)
#pragma unroll
      for (int ks = 0; ks < 2; ++ks)
        bu[j][ks] = LD8(Bb, lds_off(ks, 128 + wn * 32 + j * 16 + fm, fq));
    __builtin_amdgcn_s_barrier();
    asm volatile("s_waitcnt lgkmcnt(0)" ::: "memory");
    __builtin_amdgcn_sched_barrier(0);
    __builtin_amdgcn_s_setprio(1);
#pragma unroll
    for (int mi = 0; mi < 4; ++mi)
#pragma unroll
      for (int j = 0; j < 2; ++j)
#pragma unroll
        for (int ks = 0; ks < 2; ++ks)
          accu[mi][j] = MFMA16(a[mi][ks], bu[j][ks], accu[mi][j], 0, 0, 0);
    __builtin_amdgcn_s_setprio(0);
    __builtin_amdgcn_s_barrier();

    // ---- P3: read A-m1 | wait B(t+1), write, issue B(t+2) | MFMA u-m1 ----
#pragma unroll
    for (int i = 0; i < 4; ++i)
#pragma unroll
      for (int ks = 0; ks < 2; ++ks)
        a[i][ks] = LD8(Ab, lds_off(ks, 128 + wm * 64 + i * 16 + fm, fq));
    if (pf) {
      if (pf2) asm volatile("s_waitcnt vmcnt(8)" ::: "memory");  // B(t+1) landed, A(t+2) flying
      else     asm volatile("s_waitcnt vmcnt(0)" ::: "memory");
      writeB(bn);
      if (pf2) loadB(k2);
    }
    __builtin_amdgcn_s_barrier();
    asm volatile("s_waitcnt lgkmcnt(0)" ::: "memory");
    __builtin_amdgcn_sched_barrier(0);
    __builtin_amdgcn_s_setprio(1);
#pragma unroll
    for (int mi = 0; mi < 4; ++mi)
#pragma unroll
      for (int j = 0; j < 2; ++j)
#pragma unroll
        for (int ks = 0; ks < 2; ++ks)
          accu[4 + mi][j] = MFMA16(a[mi][ks], bu[j][ks], accu[4 + mi][j], 0, 0, 0);
    __builtin_amdgcn_s_setprio(0);
    __builtin_amdgcn_s_barrier();

    // ---- P4: MFMA g-m1 (bg regs still live) ----
    __builtin_amdgcn_s_setprio(1);
#pragma unroll
    for (int mi = 0; mi < 4; ++mi)
#pragma unroll
      for (int j = 0; j < 2; ++j)
#pragma unroll
        for (int ks = 0; ks < 2; ++ks)
          accg[4 + mi][j] = MFMA16(a[mi][ks], bg[j][ks], accg[4 + mi][j], 0, 0, 0);
    __builtin_amdgcn_s_setprio(0);
    __builtin_amdgcn_s_barrier();
  }

  // SwiGLU epilogue -> inter (bf16). Padded rows computed too (harmless).
#pragma unroll
  for (int mi = 0; mi < 8; ++mi)
#pragma unroll
    for (int j = 0; j < 2; ++j)
#pragma unroll
      for (int r = 0; r < 4; ++r) {
        float gg = accg[mi][j][r];
        float u = accu[mi][j][r];
        float v = (gg / (1.0f + __expf(-gg))) * u;
        int row = row0 + wm * 128 + mi * 16 + fq * 4 + r;
        int col = col0 + wn * 32 + j * 16 + fm;
        inter[(size_t)row * ID + col] = f2bf(v);
      }
}

// ---------------- down GEMM: A=inter bf16 (gl_lds), B=down_w fp32 (reg) -----
// C[m,h] = sum_i inter[m,i] * Wd[e,h,i]; out[token[m],h] += w[m]*C[m,h]
// Tile 256 x 256; wave owns 128 x 64. B n-quadrants interleaved:
// phys = nq*128 + wn*32 + r5 for logical row wn*64 + nq*32 + r5.
__global__ __launch_bounds__(512, 2) void moe_down(
    const unsigned short* __restrict__ inter,
    const float* __restrict__ Wd,
    float* __restrict__ out,
    const int* __restrict__ work_e, const int* __restrict__ work_r,
    const int* __restrict__ ntiles,
    const int* __restrict__ row_token, const float* __restrict__ row_weight) {
  const int tile = blockIdx.x;
  if (tile >= *ntiles) return;
  const int e = work_e[tile];
  const int row0 = work_r[tile];
  const int col0 = blockIdx.y * 256;   // h dim

  __shared__ unsigned short As[2][16384];
  __shared__ unsigned short Bs[2][16384];
  __shared__ int tok_s[256];
  __shared__ float w_s[256];

  const int tid = threadIdx.x;
  if (tid < 256) {
    tok_s[tid] = row_token[row0 + tid];
    w_s[tid] = row_weight[row0 + tid];
  }
  __syncthreads();

  const int lane = tid & 63;
  const int wave = tid >> 6;
  const int wm = wave >> 2, wn = wave & 3;
  const int p_l = lane & 7;
  const int ub  = lane >> 3;
  const int q_l = p_l ^ ub;
  const int srow = (ub << 1) | (q_l >> 2);
  const int scol = (q_l & 3) << 3;
  const int fm = lane & 15, fq = lane >> 4;

  const size_t a_base = (size_t)row0 * ID;
  const size_t b_base = ((size_t)e * HD + col0) * ID;

  const float* pBd[2];
#pragma unroll
  for (int h = 0; h < 2; ++h) {
    int bbase = ((wave >> 1) << 6) + (h << 5) + ((wave & 1) << 4);
    pBd[h] = Wd + b_base + (size_t)(bbase + srow) * ID;
  }

  f32x4 rB[2][2][2];

  auto stA = [&](int k0, int b) {      // inter bf16 -> gl_lds direct (4 loads)
#pragma unroll
    for (int h = 0; h < 2; ++h) {
      const int abase = ((wave >> 2) << 7) + (h << 6) + ((wave & 3) << 4);
      const int pp = (h << 7) + (wave << 4);
#pragma unroll
      for (int s = 0; s < 2; ++s)
        gl_lds16(inter + a_base + (size_t)(abase + srow) * ID + k0 + s * 32 + scol,
                 &As[b][s * 8192 + pp * 32]);
    }
  };
  auto loadB = [&](int k0) {
#pragma unroll
    for (int h = 0; h < 2; ++h)
#pragma unroll
      for (int s = 0; s < 2; ++s)
#pragma unroll
        for (int p = 0; p < 2; ++p)
          rB[h][s][p] = *(const f32x4*)(pBd[h] + k0 + s * 32 + scol + p * 4);
  };
  auto writeB = [&](int b) {
#pragma unroll
    for (int h = 0; h < 2; ++h) {
      const int pp = (h << 7) + (wave << 4);
#pragma unroll
      for (int s = 0; s < 2; ++s)
        *(uint4*)&Bs[b][s * 8192 + pp * 32 + lane * 8] = cvt8(rB[h][s][0], rB[h][s][1]);
    }
  };

  f32x4 zero = {0.f, 0.f, 0.f, 0.f};
  f32x4 acc[8][4];
#pragma unroll
  for (int mi = 0; mi < 8; ++mi)
#pragma unroll
    for (int j = 0; j < 4; ++j) acc[mi][j] = zero;

  // prologue: tile 0 staged; B(1) loads in flight (8)
  loadB(0);
  stA(0, 0);
  asm volatile("s_waitcnt vmcnt(0)" ::: "memory");
  writeB(0);
  loadB(64);
  asm volatile("s_waitcnt lgkmcnt(0)" ::: "memory");
  __builtin_amdgcn_s_barrier();

  bf16x8 a[4][2], b0[2][2], b1[2][2];
#pragma unroll 1
  for (int t = 0; t < NKD; ++t) {
    const int k1 = (t + 1) << 6;
    const int k2 = (t + 2) << 6;
    const bool pf = (t + 1 < NKD);
    const bool pf2 = (t + 2 < NKD);
    const unsigned short* Ab = As[t & 1];
    const unsigned short* Bb = Bs[t & 1];
    const int bn = (t & 1) ^ 1;

    // ---- P1: read A-m0 + b-n0 | issue gl_lds A(t+1) | MFMA m0n0 ----
#pragma unroll
    for (int i = 0; i < 4; ++i)
#pragma unroll
      for (int ks = 0; ks < 2; ++ks)
        a[i][ks] = LD8(Ab, lds_off(ks, wm * 64 + i * 16 + fm, fq));
#pragma unroll
    for (int j = 0; j < 2; ++j)
#pragma unroll
      for (int ks = 0; ks < 2; ++ks)
        b0[j][ks] = LD8(Bb, lds_off(ks, wn * 32 + j * 16 + fm, fq));
    if (pf) stA(k1, bn);
    __builtin_amdgcn_s_barrier();
    asm volatile("s_waitcnt lgkmcnt(0)" ::: "memory");
    __builtin_amdgcn_sched_barrier(0);
    __builtin_amdgcn_s_setprio(1);
#pragma unroll
    for (int mi = 0; mi < 4; ++mi)
#pragma unroll
      for (int j = 0; j < 2; ++j)
#pragma unroll
        for (int ks = 0; ks < 2; ++ks)
          acc[mi][j] = MFMA16(a[mi][ks], b0[j][ks], acc[mi][j], 0, 0, 0);
    __builtin_amdgcn_s_setprio(0);
    __builtin_amdgcn_s_barrier();

    // ---- P2: read b-n1 | MFMA m0n1 ----
#pragma unroll
    for (int j = 0; j < 2; ++j)
#pragma unroll
      for (int ks = 0; ks < 2; ++ks)
        b1[j][ks] = LD8(Bb, lds_off(ks, 128 + wn * 32 + j * 16 + fm, fq));
    __builtin_amdgcn_s_barrier();
    asm volatile("s_waitcnt lgkmcnt(0)" ::: "memory");
    __builtin_amdgcn_sched_barrier(0);
    __builtin_amdgcn_s_setprio(1);
#pragma unroll
    for (int mi = 0; mi < 4; ++mi)
#pragma unroll
      for (int j = 0; j < 2; ++j)
#pragma unroll
        for (int ks = 0; ks < 2; ++ks)
          acc[mi][2 + j] = MFMA16(a[mi][ks], b1[j][ks], acc[mi][2 + j], 0, 0, 0);
    __builtin_amdgcn_s_setprio(0);
    __builtin_amdgcn_s_barrier();

    // ---- P3: read A-m1 | wait B(t+1), write, issue B(t+2) | MFMA m1n1 ----
#pragma unroll
    for (int i = 0; i < 4; ++i)
#pragma unroll
      for (int ks = 0; ks < 2; ++ks)
        a[i][ks] = LD8(Ab, lds_off(ks, 128 + wm * 64 + i * 16 + fm, fq));
    if (pf) {
      asm volatile("s_waitcnt vmcnt(4)" ::: "memory");  // B(t+1) landed; A(t+1) gl_lds flying
      writeB(bn);
      if (pf2) loadB(k2);
    }
    __builtin_amdgcn_s_barrier();
    asm volatile("s_waitcnt lgkmcnt(0)" ::: "memory");
    __builtin_amdgcn_sched_barrier(0);
    __builtin_amdgcn_s_setprio(1);
#pragma unroll
    for (int mi = 0; mi < 4; ++mi)
#pragma unroll
      for (int j = 0; j < 2; ++j)
#pragma unroll
        for (int ks = 0; ks < 2; ++ks)
          acc[4 + mi][2 + j] = MFMA16(a[mi][ks], b1[j][ks], acc[4 + mi][2 + j], 0, 0, 0);
    __builtin_amdgcn_s_setprio(0);
    __builtin_amdgcn_s_barrier();

    // ---- P4: MFMA m1n0 | wait A(t+1) gl_lds landed ----
    __builtin_amdgcn_s_setprio(1);
#pragma unroll
    for (int mi = 0; mi < 4; ++mi)
#pragma unroll
      for (int j = 0; j < 2; ++j)
#pragma unroll
        for (int ks = 0; ks < 2; ++ks)
          acc[4 + mi][j] = MFMA16(a[mi][ks], b0[j][ks], acc[4 + mi][j], 0, 0, 0);
    __builtin_amdgcn_s_setprio(0);
    if (pf) {
      if (pf2) asm volatile("s_waitcnt vmcnt(8)" ::: "memory");  // A(t+1) landed; B(t+2) flying
      else     asm volatile("s_waitcnt vmcnt(0)" ::: "memory");
    }
    __builtin_amdgcn_s_barrier();
  }

#pragma unroll
  for (int mi = 0; mi < 8; ++mi)
#pragma unroll
    for (int j = 0; j < 4; ++j)
#pragma unroll
      for (int r = 0; r < 4; ++r) {
        int rl = wm * 128 + mi * 16 + fq * 4 + r;
        int tok = tok_s[rl];
        if (tok >= 0) {
          int col = col0 + wn * 64 + (j >> 1) * 32 + (j & 1) * 16 + fm;
          atomicAdd(&out[(size_t)tok * HD + col], w_s[rl] * acc[mi][j][r]);
        }
      }
}

// ---------------- host ------------------------------------------------------
extern "C" void kernel_launch(void* const* d_in, const int* in_sizes, int n_in,
                              void* d_out, int out_size, void* d_ws, size_t ws_size,
                              hipStream_t stream) {
  const float* hidden = (const float*)d_in[0];
  const int* topk_idx = (const int*)d_in[1];
  const float* topk_w = (const float*)d_in[2];
  const float* gate_w = (const float*)d_in[3];
  const float* up_w = (const float*)d_in[4];
  const float* down_w = (const float*)d_in[5];
  float* out = (float*)d_out;

  char* ws = (char*)d_ws;
  size_t o_int = 0;
  size_t o_tok = o_int + (size_t)MAXR * ID * 2;
  size_t o_wgt = o_tok + (size_t)MAXR * 4;
  size_t o_wrk = o_wgt + (size_t)MAXR * 4;

  unsigned short* inter = (unsigned short*)(ws + o_int);
  int* row_token = (int*)(ws + o_tok);
  float* row_weight = (float*)(ws + o_wgt);
  int* work_e = (int*)(ws + o_wrk);
  int* work_r = work_e + MAXT;
  int* ntiles = work_r + MAXT;

  hipMemsetAsync(out, 0, (size_t)T_TOK * HD * 4, stream);

  moe_route<<<1, 256, 0, stream>>>(topk_idx, topk_w, work_e, work_r, ntiles,
                                   row_token, row_weight);

  moe_gateup<<<NGEMM_GU, 512, 0, stream>>>(
      hidden, gate_w, up_w, inter, work_e, work_r, ntiles, row_token);

  dim3 gridB(NTILE_G, HD / 256);   // 40 x 8
  moe_down<<<gridB, 512, 0, stream>>>(inter, down_w, out, work_e, work_r, ntiles,
                                      row_token, row_weight);
}